// Round 1
// baseline (1458.413 us; speedup 1.0000x reference)
//
#include <hip/hip_runtime.h>
#include <hip/hip_bf16.h>
#include <math.h>

#define SEQ 2048
#define DKH 64
#define NH 16
#define NEGV -10000.0f
#define LIST_CAP 160

__device__ __forceinline__ unsigned int f2k(float f) {
  unsigned int u = __float_as_uint(f);
  return (u & 0x80000000u) ? ~u : (u | 0x80000000u);
}
__device__ __forceinline__ float k2f(unsigned int k) {
  unsigned int u = (k & 0x80000000u) ? (k & 0x7FFFFFFFu) : ~k;
  return __uint_as_float(u);
}

// ---------------------------------------------------------------------------
// GEMM: C[m,n] = sum_k X[m,k] * W[n,k] + bias[n];  M=4096, N=1024, K=1024.
// qkv_mode=1: write out[(b*16+h)*2048 + s][dk]  (b,h,s,dk layout, h=n>>6)
// qkv_mode=0: write out[m][n] plain (B,S,D)
// ---------------------------------------------------------------------------
__global__ __launch_bounds__(256)
void gemm_proj(const float* __restrict__ X, const float* __restrict__ W,
               const float* __restrict__ bias, float* __restrict__ out,
               int qkv_mode)
{
  __shared__ float Xs[16][68];
  __shared__ float Ws[16][68];
  const int t  = threadIdx.x;
  const int nb = blockIdx.x & 15;
  const int mb = blockIdx.x >> 4;
  const int m0 = mb * 64, n0 = nb * 64;
  const int tx = t & 15, ty = t >> 4;
  const int lm = t >> 2;
  const int lk = (t & 3) * 4;
  const float* xsrc = X + (size_t)(m0 + lm) * 1024 + lk;
  const float* wsrc = W + (size_t)(n0 + lm) * 1024 + lk;

  float acc[4][4];
#pragma unroll
  for (int i = 0; i < 4; i++)
#pragma unroll
    for (int j = 0; j < 4; j++) acc[i][j] = 0.0f;

  for (int k0 = 0; k0 < 1024; k0 += 16) {
    float4 xv = *(const float4*)(xsrc + k0);
    float4 wv = *(const float4*)(wsrc + k0);
    __syncthreads();
    Xs[lk+0][lm] = xv.x; Xs[lk+1][lm] = xv.y; Xs[lk+2][lm] = xv.z; Xs[lk+3][lm] = xv.w;
    Ws[lk+0][lm] = wv.x; Ws[lk+1][lm] = wv.y; Ws[lk+2][lm] = wv.z; Ws[lk+3][lm] = wv.w;
    __syncthreads();
#pragma unroll
    for (int kk = 0; kk < 16; kk++) {
      float4 a = *(const float4*)&Xs[kk][ty*4];
      float4 b = *(const float4*)&Ws[kk][tx*4];
      acc[0][0] = fmaf(a.x, b.x, acc[0][0]);
      acc[0][1] = fmaf(a.x, b.y, acc[0][1]);
      acc[0][2] = fmaf(a.x, b.z, acc[0][2]);
      acc[0][3] = fmaf(a.x, b.w, acc[0][3]);
      acc[1][0] = fmaf(a.y, b.x, acc[1][0]);
      acc[1][1] = fmaf(a.y, b.y, acc[1][1]);
      acc[1][2] = fmaf(a.y, b.z, acc[1][2]);
      acc[1][3] = fmaf(a.y, b.w, acc[1][3]);
      acc[2][0] = fmaf(a.z, b.x, acc[2][0]);
      acc[2][1] = fmaf(a.z, b.y, acc[2][1]);
      acc[2][2] = fmaf(a.z, b.z, acc[2][2]);
      acc[2][3] = fmaf(a.z, b.w, acc[2][3]);
      acc[3][0] = fmaf(a.w, b.x, acc[3][0]);
      acc[3][1] = fmaf(a.w, b.y, acc[3][1]);
      acc[3][2] = fmaf(a.w, b.z, acc[3][2]);
      acc[3][3] = fmaf(a.w, b.w, acc[3][3]);
    }
  }

  float4 bv = *(const float4*)(bias + n0 + tx*4);
#pragma unroll
  for (int i = 0; i < 4; i++) {
    int m = m0 + ty*4 + i;
    float4 r;
    r.x = acc[i][0] + bv.x;
    r.y = acc[i][1] + bv.y;
    r.z = acc[i][2] + bv.z;
    r.w = acc[i][3] + bv.w;
    size_t off;
    if (qkv_mode) {
      int bb = m >> 11, s = m & 2047;
      off = ((size_t)(bb * NH + nb) * SEQ + s) * DKH + tx*4;
    } else {
      off = (size_t)m * 1024 + n0 + tx*4;
    }
    *(float4*)(out + off) = r;
  }
}

// ---------------------------------------------------------------------------
// Attention with exact causal top-64 thresholding.
// One block = 8 rows of one (b,h). Scores cached in LDS; selection per wave
// (2 rows/wave) with key-space bisection + bitonic candidate sort; sparse PV.
// ---------------------------------------------------------------------------
struct AttnSmem {
  float scores[8][SEQ];        // 64 KB: scores then overwritten with p
  float ktile[32][65];         // pad 65 -> bank (j+d)%32, conflict-free
  union {
    float qstage[8][64];       // only used before QK loop
    struct {
      unsigned short lists[8][LIST_CAP];
      float cand[4][64];
      int   candcnt[4];
    } sel;                     // only used after QK loop
  } u;
};

__global__ __launch_bounds__(256)
void attn_topk(const float* __restrict__ qp, const float* __restrict__ kp,
               const float* __restrict__ vp, float* __restrict__ ao)
{
  __shared__ AttnSmem sm;
  const int t    = threadIdx.x;
  const int lane = t & 63;
  const int w    = t >> 6;
  const int bh   = blockIdx.x >> 8;
  const int rb   = blockIdx.x & 255;
  const int i0   = rb * 8;
  const float* qbase = qp + (size_t)bh * SEQ * DKH;
  const float* kbase = kp + (size_t)bh * SEQ * DKH;
  const float* vbase = vp + (size_t)bh * SEQ * DKH;

  // stage q rows (8 x 64 floats), then preload this thread's q row to regs
  {
    float2 v = *(const float2*)(qbase + (size_t)i0 * DKH + t * 2);
    ((float2*)&sm.u.qstage[0][0])[t] = v;
  }
  __syncthreads();
  const int rq   = t >> 5;   // 0..7 : row this thread computes in QK
  const int jq   = t & 31;   // local column in 32-wide tile
  const int irow = i0 + rq;
  float qreg[64];
#pragma unroll
  for (int c = 0; c < 16; c++) {
    float4 qv = *(const float4*)&sm.u.qstage[rq][c*4];
    qreg[c*4+0] = qv.x; qreg[c*4+1] = qv.y; qreg[c*4+2] = qv.z; qreg[c*4+3] = qv.w;
  }
  __syncthreads();  // qstage (aliased by sel) is free after this point

  // ---- phase 1: QK^T into LDS scores (causal-masked, scaled by 1/8) ----
  const int ntiles = (i0 >> 5) + 1;   // tiles with j0 <= i0+7
  for (int tt = 0; tt < ntiles; tt++) {
    const int j0 = tt * 32;
    {
      const int jk = t >> 3;
      const int c0 = (t & 7) * 8;
      const float* src = kbase + (size_t)(j0 + jk) * DKH + c0;
      float4 va = *(const float4*)src;
      float4 vb = *(const float4*)(src + 4);
      float* dst = &sm.ktile[jk][c0];
      dst[0]=va.x; dst[1]=va.y; dst[2]=va.z; dst[3]=va.w;
      dst[4]=vb.x; dst[5]=vb.y; dst[6]=vb.z; dst[7]=vb.w;
    }
    __syncthreads();
    {
      const float* krow = &sm.ktile[jq][0];
      float a0=0.f, a1=0.f, a2=0.f, a3=0.f;
#pragma unroll
      for (int d = 0; d < 64; d += 4) {
        a0 = fmaf(qreg[d+0], krow[d+0], a0);
        a1 = fmaf(qreg[d+1], krow[d+1], a1);
        a2 = fmaf(qreg[d+2], krow[d+2], a2);
        a3 = fmaf(qreg[d+3], krow[d+3], a3);
      }
      const int j = j0 + jq;
      sm.scores[rq][j] = (j <= irow) ? ((a0+a1) + (a2+a3)) * 0.125f : NEGV;
    }
    __syncthreads();
  }
  {
    const int base = ntiles * 32;      // fill untouched columns with NEG
    for (int x = t; x < (SEQ - base) * 8; x += 256)
      sm.scores[x & 7][base + (x >> 3)] = NEGV;
  }
  __syncthreads();

  // ---- phase 2 (wave-local): exact top-64 threshold, softmax, sparse PV ----
  const int bb = bh >> 4, hh = bh & 15;
  for (int rr = 0; rr < 2; rr++) {
    const int r = 2*w + rr;
    const int i = i0 + r;

    unsigned int keys[32];
    float vmax = NEGV, vmin = 3.4e38f;
#pragma unroll
    for (int u2 = 0; u2 < 32; u2++) {
      float v = sm.scores[r][lane + 64*u2];
      vmax = fmaxf(vmax, v);
      if (v > -5000.0f) vmin = fminf(vmin, v);
      keys[u2] = f2k(v);
    }
#pragma unroll
    for (int off = 32; off; off >>= 1) {
      vmax = fmaxf(vmax, __shfl_xor(vmax, off));
      vmin = fminf(vmin, __shfl_xor(vmin, off));
    }

    float vk;
    if (i + 1 <= 64) {
      vk = NEGV;  // fewer than 65 valid: NEG is the 64th value -> keep all
    } else {
      unsigned int ka = f2k(vmin);       // count(>=ka) = i+1 >= 65
      unsigned int kb = f2k(vmax) + 1u;  // count(>=kb) = 0
      int ca = i + 1, cb = 0;
      int guard = 0;
      while (kb - ka > 1u && (ca - cb) > 56 && guard < 64) {
        guard++;
        float fm = 0.5f * (k2f(ka) + k2f(kb));
        unsigned int km = f2k(fm);
        if (km <= ka || km >= kb) km = ka + ((kb - ka) >> 1);
        int cnt = 0;
#pragma unroll
        for (int u2 = 0; u2 < 32; u2++) cnt += (keys[u2] >= km) ? 1 : 0;
#pragma unroll
        for (int off = 32; off; off >>= 1) cnt += __shfl_xor(cnt, off);
        if (cnt >= 64) { ka = km; ca = cnt; } else { kb = km; cb = cnt; }
      }
      if (kb - ka == 1u || (ca - cb) > 64) {
        vk = k2f(ka);   // exact when interval collapsed (dup-safe)
      } else {
        if (lane == 0) sm.u.sel.candcnt[w] = 0;
        __threadfence_block();
#pragma unroll
        for (int u2 = 0; u2 < 32; u2++) {
          unsigned int kx = keys[u2];
          if (kx >= ka && kx < kb) {
            int pos = atomicAdd(&sm.u.sel.candcnt[w], 1);
            sm.u.sel.cand[w][pos] = k2f(kx);
          }
        }
        __threadfence_block();
        int nc = sm.u.sel.candcnt[w];
        float cv = (lane < nc) ? sm.u.sel.cand[w][lane] : -3.4e38f;
        // 64-lane bitonic sort, ascending
        for (int ks = 2; ks <= 64; ks <<= 1) {
          for (int j2 = ks >> 1; j2 > 0; j2 >>= 1) {
            float other = __shfl_xor(cv, j2);
            bool up    = ((lane & ks) == 0);
            bool lower = ((lane & j2) == 0);
            float mn = fminf(cv, other), mx = fmaxf(cv, other);
            cv = (up == lower) ? mn : mx;
          }
        }
        int need = 64 - cb;            // rank among candidates
        vk = __shfl(cv, 64 - need);
      }
    }

    // softmax (ref semantics: p = s>=vk ? exp(s-max) : 0) + kept-index list
    float z = 0.0f;
    int cnt_base = 0;
    for (int u2 = 0; u2 < 32; u2++) {
      int j = lane + 64*u2;
      float sv = k2f(keys[u2]);
      float p = (sv >= vk) ? __expf(sv - vmax) : 0.0f;
      sm.scores[r][j] = p;
      z += p;
      unsigned long long mask = __ballot(p > 0.0f);
      if (p > 0.0f) {
        int pos = cnt_base + __popcll(mask & ((1ull << lane) - 1ull));
        if (pos < LIST_CAP) sm.u.sel.lists[r][pos] = (unsigned short)j;
      }
      cnt_base += __popcll(mask);
    }
#pragma unroll
    for (int off = 32; off; off >>= 1) z += __shfl_xor(z, off);
    const float rz = 1.0f / z;

    // sparse PV: lane = head dim; gather kept V rows (coalesced 256B rows)
    float acc = 0.0f;
    if (cnt_base <= LIST_CAP) {
      int u2 = 0;
      for (; u2 + 4 <= cnt_base; u2 += 4) {
        int j0_ = sm.u.sel.lists[r][u2+0];
        int j1_ = sm.u.sel.lists[r][u2+1];
        int j2_ = sm.u.sel.lists[r][u2+2];
        int j3_ = sm.u.sel.lists[r][u2+3];
        float p0 = sm.scores[r][j0_], p1 = sm.scores[r][j1_];
        float p2 = sm.scores[r][j2_], p3 = sm.scores[r][j3_];
        float v0 = vbase[(size_t)j0_ * DKH + lane];
        float v1 = vbase[(size_t)j1_ * DKH + lane];
        float v2 = vbase[(size_t)j2_ * DKH + lane];
        float v3 = vbase[(size_t)j3_ * DKH + lane];
        acc = fmaf(p0, v0, acc); acc = fmaf(p1, v1, acc);
        acc = fmaf(p2, v2, acc); acc = fmaf(p3, v3, acc);
      }
      for (; u2 < cnt_base; u2++) {
        int jx = sm.u.sel.lists[r][u2];
        acc = fmaf(sm.scores[r][jx], vbase[(size_t)jx * DKH + lane], acc);
      }
    } else {                      // overflow fallback (ties pathology): dense
      for (int jx = 0; jx <= i; jx++)
        acc = fmaf(sm.scores[r][jx], vbase[(size_t)jx * DKH + lane], acc);
    }
    ao[((size_t)(bb * SEQ + i) * NH + hh) * DKH + lane] = acc * rz;
  }
}

// ---------------------------------------------------------------------------
extern "C" void kernel_launch(void* const* d_in, const int* in_sizes, int n_in,
                              void* d_out, int out_size, void* d_ws, size_t ws_size,
                              hipStream_t stream)
{
  const float* query = (const float*)d_in[0];
  const float* key   = (const float*)d_in[1];
  const float* value = (const float*)d_in[2];
  const float* Wq    = (const float*)d_in[3];
  const float* bq    = (const float*)d_in[4];
  const float* Wk    = (const float*)d_in[5];
  const float* bk    = (const float*)d_in[6];
  const float* Wv    = (const float*)d_in[7];
  const float* bv    = (const float*)d_in[8];
  const float* Wo    = (const float*)d_in[9];
  const float* bo    = (const float*)d_in[10];

  // ws: qp | kp | vp | ao, each B*H*S*DK = 4,194,304 floats (16 MB); 64 MB total
  float* ws = (float*)d_ws;
  float* qp = ws;
  float* kp = ws + (size_t)4194304;
  float* vp = ws + (size_t)8388608;
  float* ao = ws + (size_t)12582912;
  float* out = (float*)d_out;

  hipLaunchKernelGGL(gemm_proj, dim3(1024), dim3(256), 0, stream, query, Wq, bq, qp, 1);
  hipLaunchKernelGGL(gemm_proj, dim3(1024), dim3(256), 0, stream, key,   Wk, bk, kp, 1);
  hipLaunchKernelGGL(gemm_proj, dim3(1024), dim3(256), 0, stream, value, Wv, bv, vp, 1);
  hipLaunchKernelGGL(attn_topk, dim3(8192), dim3(256), 0, stream, qp, kp, vp, ao);
  hipLaunchKernelGGL(gemm_proj, dim3(1024), dim3(256), 0, stream, ao, Wo, bo, out, 0);
}

// Round 2
// 1327.226 us; speedup vs baseline: 1.0988x; 1.0988x over previous
//
#include <hip/hip_runtime.h>
#include <hip/hip_bf16.h>
#include <math.h>

#define SEQ 2048
#define DKH 64
#define NH 16
#define NEGV -10000.0f
#define LIST_CAP 160

typedef __attribute__((ext_vector_type(8))) short short8;
typedef __attribute__((ext_vector_type(4))) float f32x4;

__device__ __forceinline__ unsigned int f2k(float f) {
  unsigned int u = __float_as_uint(f);
  return (u & 0x80000000u) ? ~u : (u | 0x80000000u);
}
__device__ __forceinline__ float k2f(unsigned int k) {
  unsigned int u = (k & 0x80000000u) ? (k & 0x7FFFFFFFu) : ~k;
  return __uint_as_float(u);
}

// ---------------------------------------------------------------------------
// GEMM: C[m,n] = sum_k X[m,k] * W[n,k] + bias[n];  M=4096, N=1024, K=1024.
// mode 0: outF[m][n] fp32 plain (B,S,D)
// mode 1: outF[(b*16+h)*2048+s][dk] fp32 (b,h,s,dk), h = n>>6
// mode 2: outHi/outLo bf16 hi/lo planes, (b,h,s,dk) layout (for q,k)
// ---------------------------------------------------------------------------
__global__ __launch_bounds__(256)
void gemm_proj(const float* __restrict__ X, const float* __restrict__ W,
               const float* __restrict__ bias, float* __restrict__ outF,
               unsigned short* __restrict__ outHi, unsigned short* __restrict__ outLo,
               int mode)
{
  __shared__ float Xs[16][68];
  __shared__ float Ws[16][68];
  const int t  = threadIdx.x;
  const int nb = blockIdx.x & 15;
  const int mb = blockIdx.x >> 4;
  const int m0 = mb * 64, n0 = nb * 64;
  const int tx = t & 15, ty = t >> 4;
  const int lm = t >> 2;
  const int lk = (t & 3) * 4;
  const float* xsrc = X + (size_t)(m0 + lm) * 1024 + lk;
  const float* wsrc = W + (size_t)(n0 + lm) * 1024 + lk;

  float acc[4][4];
#pragma unroll
  for (int i = 0; i < 4; i++)
#pragma unroll
    for (int j = 0; j < 4; j++) acc[i][j] = 0.0f;

  for (int k0 = 0; k0 < 1024; k0 += 16) {
    float4 xv = *(const float4*)(xsrc + k0);
    float4 wv = *(const float4*)(wsrc + k0);
    __syncthreads();
    Xs[lk+0][lm] = xv.x; Xs[lk+1][lm] = xv.y; Xs[lk+2][lm] = xv.z; Xs[lk+3][lm] = xv.w;
    Ws[lk+0][lm] = wv.x; Ws[lk+1][lm] = wv.y; Ws[lk+2][lm] = wv.z; Ws[lk+3][lm] = wv.w;
    __syncthreads();
#pragma unroll
    for (int kk = 0; kk < 16; kk++) {
      float4 a = *(const float4*)&Xs[kk][ty*4];
      float4 b = *(const float4*)&Ws[kk][tx*4];
      acc[0][0] = fmaf(a.x, b.x, acc[0][0]);
      acc[0][1] = fmaf(a.x, b.y, acc[0][1]);
      acc[0][2] = fmaf(a.x, b.z, acc[0][2]);
      acc[0][3] = fmaf(a.x, b.w, acc[0][3]);
      acc[1][0] = fmaf(a.y, b.x, acc[1][0]);
      acc[1][1] = fmaf(a.y, b.y, acc[1][1]);
      acc[1][2] = fmaf(a.y, b.z, acc[1][2]);
      acc[1][3] = fmaf(a.y, b.w, acc[1][3]);
      acc[2][0] = fmaf(a.z, b.x, acc[2][0]);
      acc[2][1] = fmaf(a.z, b.y, acc[2][1]);
      acc[2][2] = fmaf(a.z, b.z, acc[2][2]);
      acc[2][3] = fmaf(a.z, b.w, acc[2][3]);
      acc[3][0] = fmaf(a.w, b.x, acc[3][0]);
      acc[3][1] = fmaf(a.w, b.y, acc[3][1]);
      acc[3][2] = fmaf(a.w, b.z, acc[3][2]);
      acc[3][3] = fmaf(a.w, b.w, acc[3][3]);
    }
  }

  float4 bv = *(const float4*)(bias + n0 + tx*4);
#pragma unroll
  for (int i = 0; i < 4; i++) {
    int m = m0 + ty*4 + i;
    float r0 = acc[i][0] + bv.x;
    float r1 = acc[i][1] + bv.y;
    float r2 = acc[i][2] + bv.z;
    float r3 = acc[i][3] + bv.w;
    if (mode == 2) {
      int bb = m >> 11, s = m & 2047;
      size_t off = ((size_t)(bb * NH + nb) * SEQ + s) * DKH + tx*4;
      float rr[4] = {r0, r1, r2, r3};
      ushort4 h, l;
      unsigned short hs[4], ls[4];
#pragma unroll
      for (int j = 0; j < 4; j++) {
        unsigned int u = __float_as_uint(rr[j]);
        hs[j] = (unsigned short)(u >> 16);
        float hf = __uint_as_float(u & 0xffff0000u);
        float lf = rr[j] - hf;
        ls[j] = (unsigned short)(__float_as_uint(lf) >> 16);
      }
      h.x = hs[0]; h.y = hs[1]; h.z = hs[2]; h.w = hs[3];
      l.x = ls[0]; l.y = ls[1]; l.z = ls[2]; l.w = ls[3];
      *(ushort4*)(outHi + off) = h;
      *(ushort4*)(outLo + off) = l;
    } else {
      size_t off;
      if (mode == 1) {
        int bb = m >> 11, s = m & 2047;
        off = ((size_t)(bb * NH + nb) * SEQ + s) * DKH + tx*4;
      } else {
        off = (size_t)m * 1024 + n0 + tx*4;
      }
      float4 r; r.x = r0; r.y = r1; r.z = r2; r.w = r3;
      *(float4*)(outF + off) = r;
    }
  }
}

// ---------------------------------------------------------------------------
// Attention: split-bf16 MFMA QK^T (3-pass hi/lo, fp32-accurate to ~2^-15),
// exact causal top-64 thresholding, sparse PV.
// One block = 8 rows of one (b,h). Scores in LDS (64 KB).
// Phase 1: per-wave 16x16x32 MFMA tiles (rows 8..15 of tile wasted),
// A/B fragments straight from global (K is L2-resident), no inner barriers.
// ---------------------------------------------------------------------------
struct AttnSmem {
  float scores[8][SEQ];            // 64 KB; scores then p
  unsigned short lists[8][LIST_CAP];
  float cand[4][64];
  int   candcnt[4];
};

__global__ __launch_bounds__(256)
void attn_topk(const unsigned short* __restrict__ qhi, const unsigned short* __restrict__ qlo,
               const unsigned short* __restrict__ khi, const unsigned short* __restrict__ klo,
               const float* __restrict__ vp, float* __restrict__ ao)
{
  __shared__ AttnSmem sm;
  const int t    = threadIdx.x;
  const int lane = t & 63;
  const int w    = t >> 6;
  const int bh   = blockIdx.x >> 8;
  const int rb   = blockIdx.x & 255;
  const int i0   = rb * 8;
  const size_t bhoff = (size_t)bh * SEQ * DKH;
  const unsigned short* qh = qhi + bhoff;
  const unsigned short* ql = qlo + bhoff;
  const unsigned short* kh = khi + bhoff;
  const unsigned short* kl = klo + bhoff;
  const float* vbase = vp + bhoff;

  // ---- phase 1: MFMA QK^T into LDS scores ----
  // A-frag: lane holds q[i0 + (lane&15)][c*32 + (lane>>4)*8 .. +8]
  // B-frag: lane holds k[j0 + (lane&15)][c*32 + (lane>>4)*8 .. +8]
  // C: row m = (lane>>4)*4 + reg (only m<8 valid), col n = lane&15
  const int am   = lane & 15;
  const int aq   = lane >> 4;
  const int dofs = aq * 8;

  short8 a_hi[2], a_lo[2];
#pragma unroll
  for (int c = 0; c < 2; c++) {
    size_t off = (size_t)(i0 + am) * DKH + c*32 + dofs;   // rows i0..i0+15 (8 over-read, padded by plane order)
    a_hi[c] = *(const short8*)(qh + off);
    a_lo[c] = *(const short8*)(ql + off);
  }

  const int T = (i0 >> 4) + 1;   // 16-col tiles with j0 <= i0+7
  short8 b_hi[2], b_lo[2];
  int tt = w;
  if (tt < T) {
#pragma unroll
    for (int c = 0; c < 2; c++) {
      size_t off = (size_t)(tt*16 + am) * DKH + c*32 + dofs;
      b_hi[c] = *(const short8*)(kh + off);
      b_lo[c] = *(const short8*)(kl + off);
    }
  }
  for (; tt < T; tt += 4) {
    short8 n_hi[2], n_lo[2];
    const int tn = tt + 4;
    if (tn < T) {
#pragma unroll
      for (int c = 0; c < 2; c++) {
        size_t off = (size_t)(tn*16 + am) * DKH + c*32 + dofs;
        n_hi[c] = *(const short8*)(kh + off);
        n_lo[c] = *(const short8*)(kl + off);
      }
    } else {
#pragma unroll
      for (int c = 0; c < 2; c++) { n_hi[c] = b_hi[c]; n_lo[c] = b_lo[c]; }
    }
    f32x4 C = {0.0f, 0.0f, 0.0f, 0.0f};
#pragma unroll
    for (int c = 0; c < 2; c++) {
      C = __builtin_amdgcn_mfma_f32_16x16x32_bf16(a_hi[c], b_hi[c], C, 0, 0, 0);
      C = __builtin_amdgcn_mfma_f32_16x16x32_bf16(a_lo[c], b_hi[c], C, 0, 0, 0);
      C = __builtin_amdgcn_mfma_f32_16x16x32_bf16(a_hi[c], b_lo[c], C, 0, 0, 0);
    }
    if (aq < 2) {
      const int j = tt*16 + am;
#pragma unroll
      for (int reg = 0; reg < 4; reg++) {
        const int rr = aq*4 + reg;
        sm.scores[rr][j] = (j <= i0 + rr) ? C[reg] * 0.125f : NEGV;
      }
    }
#pragma unroll
    for (int c = 0; c < 2; c++) { b_hi[c] = n_hi[c]; b_lo[c] = n_lo[c]; }
  }
  __syncthreads();

  // ---- phase 2 (wave-local): exact top-64 threshold, softmax, sparse PV ----
  const int bb = bh >> 4, hh = bh & 15;
  for (int rr2 = 0; rr2 < 2; rr2++) {
    const int r = 2*w + rr2;
    const int i = i0 + r;
    const int umax = i >> 6;       // keys beyond umax never touched

    unsigned int keys[32];
    float vmax = NEGV, vmin = 3.4e38f;
#pragma unroll
    for (int u2 = 0; u2 < 32; u2++) {
      if (u2 > umax) break;
      const int j = lane + 64*u2;
      float v = (j <= i) ? sm.scores[r][j] : NEGV;
      vmax = fmaxf(vmax, v);
      if (v > -5000.0f) vmin = fminf(vmin, v);
      keys[u2] = f2k(v);
    }
#pragma unroll
    for (int off = 32; off; off >>= 1) {
      vmax = fmaxf(vmax, __shfl_xor(vmax, off));
      vmin = fminf(vmin, __shfl_xor(vmin, off));
    }

    float vk;
    if (i + 1 <= 64) {
      vk = NEGV;  // <=64 valid: threshold is NEG -> keep all valid
    } else {
      unsigned int ka = f2k(vmin);       // count(>=ka) = i+1 >= 65
      unsigned int kb = f2k(vmax) + 1u;  // count(>=kb) = 0
      int ca = i + 1, cb = 0;
      int guard = 0;
      while (kb - ka > 1u && (ca - cb) > 56 && guard < 64) {
        guard++;
        float fm = 0.5f * (k2f(ka) + k2f(kb));
        unsigned int km = f2k(fm);
        if (km <= ka || km >= kb) km = ka + ((kb - ka) >> 1);
        int cnt = 0;
#pragma unroll
        for (int u2 = 0; u2 < 32; u2++) {
          if (u2 > umax) break;
          cnt += (keys[u2] >= km) ? 1 : 0;
        }
#pragma unroll
        for (int off = 32; off; off >>= 1) cnt += __shfl_xor(cnt, off);
        if (cnt >= 64) { ka = km; ca = cnt; } else { kb = km; cb = cnt; }
      }
      if (kb - ka == 1u || (ca - cb) > 64) {
        vk = k2f(ka);   // interval collapsed (duplicates) -> exact
      } else {
        if (lane == 0) sm.candcnt[w] = 0;
        __threadfence_block();
#pragma unroll
        for (int u2 = 0; u2 < 32; u2++) {
          if (u2 > umax) break;
          unsigned int kx = keys[u2];
          if (kx >= ka && kx < kb) {
            int pos = atomicAdd(&sm.candcnt[w], 1);
            sm.cand[w][pos] = k2f(kx);
          }
        }
        __threadfence_block();
        int nc = sm.candcnt[w];
        float cv = (lane < nc) ? sm.cand[w][lane] : -3.4e38f;
        for (int ks = 2; ks <= 64; ks <<= 1) {
          for (int j2 = ks >> 1; j2 > 0; j2 >>= 1) {
            float other = __shfl_xor(cv, j2);
            bool up    = ((lane & ks) == 0);
            bool lower = ((lane & j2) == 0);
            float mn = fminf(cv, other), mx = fmaxf(cv, other);
            cv = (up == lower) ? mn : mx;
          }
        }
        int need = 64 - cb;
        vk = __shfl(cv, 64 - need);
      }
    }

    // softmax (p = s>=vk ? exp(s-max) : 0) + kept-index list
    float z = 0.0f;
    int cnt_base = 0;
#pragma unroll
    for (int u2 = 0; u2 < 32; u2++) {
      if (u2 > umax) break;
      const int j = lane + 64*u2;
      float sv = k2f(keys[u2]);
      float p = (sv >= vk) ? __expf(sv - vmax) : 0.0f;
      sm.scores[r][j] = p;
      z += p;
      unsigned long long mask = __ballot(p > 0.0f);
      if (p > 0.0f) {
        int pos = cnt_base + __popcll(mask & ((1ull << lane) - 1ull));
        if (pos < LIST_CAP) sm.lists[r][pos] = (unsigned short)j;
      }
      cnt_base += __popcll(mask);
    }
#pragma unroll
    for (int off = 32; off; off >>= 1) z += __shfl_xor(z, off);
    const float rz = 1.0f / z;

    // sparse PV: lane = head dim; gather kept V rows (coalesced 256B rows)
    float acc = 0.0f;
    if (cnt_base <= LIST_CAP) {
      int u2 = 0;
      for (; u2 + 4 <= cnt_base; u2 += 4) {
        int j0_ = sm.lists[r][u2+0];
        int j1_ = sm.lists[r][u2+1];
        int j2_ = sm.lists[r][u2+2];
        int j3_ = sm.lists[r][u2+3];
        float p0 = sm.scores[r][j0_], p1 = sm.scores[r][j1_];
        float p2 = sm.scores[r][j2_], p3 = sm.scores[r][j3_];
        float v0 = vbase[(size_t)j0_ * DKH + lane];
        float v1 = vbase[(size_t)j1_ * DKH + lane];
        float v2 = vbase[(size_t)j2_ * DKH + lane];
        float v3 = vbase[(size_t)j3_ * DKH + lane];
        acc = fmaf(p0, v0, acc); acc = fmaf(p1, v1, acc);
        acc = fmaf(p2, v2, acc); acc = fmaf(p3, v3, acc);
      }
      for (; u2 < cnt_base; u2++) {
        int jx = sm.lists[r][u2];
        acc = fmaf(sm.scores[r][jx], vbase[(size_t)jx * DKH + lane], acc);
      }
    } else {                      // ties pathology fallback: dense
      for (int jx = 0; jx <= i; jx++)
        acc = fmaf(sm.scores[r][jx], vbase[(size_t)jx * DKH + lane], acc);
    }
    ao[((size_t)(bb * SEQ + i) * NH + hh) * DKH + lane] = acc * rz;
  }
}

// ---------------------------------------------------------------------------
extern "C" void kernel_launch(void* const* d_in, const int* in_sizes, int n_in,
                              void* d_out, int out_size, void* d_ws, size_t ws_size,
                              hipStream_t stream)
{
  const float* query = (const float*)d_in[0];
  const float* key   = (const float*)d_in[1];
  const float* value = (const float*)d_in[2];
  const float* Wq    = (const float*)d_in[3];
  const float* bq    = (const float*)d_in[4];
  const float* Wk    = (const float*)d_in[5];
  const float* bk    = (const float*)d_in[6];
  const float* Wv    = (const float*)d_in[7];
  const float* bv    = (const float*)d_in[8];
  const float* Wo    = (const float*)d_in[9];
  const float* bo    = (const float*)d_in[10];

  // ws (64 MB): q_hi(8) q_lo(8) k_hi(8) k_lo(8) v_f32(16) ao_f32(16)
  // plane order makes the 8-row q over-read in phase 1 land in the next plane.
  const size_t NE = (size_t)4194304;   // B*H*S*DK
  unsigned short* q_hi = (unsigned short*)d_ws;
  unsigned short* q_lo = q_hi + NE;
  unsigned short* k_hi = q_lo + NE;
  unsigned short* k_lo = k_hi + NE;
  float* vpf = (float*)(k_lo + NE);
  float* aop = vpf + NE;
  float* out = (float*)d_out;

  hipLaunchKernelGGL(gemm_proj, dim3(1024), dim3(256), 0, stream, query, Wq, bq, (float*)nullptr, q_hi, q_lo, 2);
  hipLaunchKernelGGL(gemm_proj, dim3(1024), dim3(256), 0, stream, key,   Wk, bk, (float*)nullptr, k_hi, k_lo, 2);
  hipLaunchKernelGGL(gemm_proj, dim3(1024), dim3(256), 0, stream, value, Wv, bv, vpf, (unsigned short*)nullptr, (unsigned short*)nullptr, 1);
  hipLaunchKernelGGL(attn_topk, dim3(8192), dim3(256), 0, stream, q_hi, q_lo, k_hi, k_lo, vpf, aop);
  hipLaunchKernelGGL(gemm_proj, dim3(1024), dim3(256), 0, stream, aop, Wo, bo, out, (unsigned short*)nullptr, (unsigned short*)nullptr, 0);
}

// Round 3
// 1030.239 us; speedup vs baseline: 1.4156x; 1.2883x over previous
//
#include <hip/hip_runtime.h>
#include <hip/hip_bf16.h>
#include <math.h>

#define SEQ 2048
#define DKH 64
#define NH 16
#define NEGV -10000.0f
#define LIST_CAP 160

typedef __attribute__((ext_vector_type(8))) short short8;
typedef __attribute__((ext_vector_type(4))) float f32x4;

__device__ __forceinline__ unsigned int f2k(float f) {
  unsigned int u = __float_as_uint(f);
  return (u & 0x80000000u) ? ~u : (u | 0x80000000u);
}
__device__ __forceinline__ float k2f(unsigned int k) {
  unsigned int u = (k & 0x80000000u) ? (k & 0x7FFFFFFFu) : ~k;
  return __uint_as_float(u);
}
__device__ __forceinline__ int lanecnt_lt(unsigned long long m) {
  return __builtin_amdgcn_mbcnt_hi((unsigned int)(m >> 32),
         __builtin_amdgcn_mbcnt_lo((unsigned int)m, 0));
}

// ---------------------------------------------------------------------------
// GEMM: C[m,n] = sum_k X[m,k] * W[n,k] + bias[n];  M=4096, N=1024, K=1024.
// mode 0: outF[m][n] fp32 plain (B,S,D)
// mode 1: outF[(b*16+h)*2048+s][dk] fp32 (b,h,s,dk), h = n>>6
// mode 2: outHi/outLo bf16 hi/lo planes, (b,h,s,dk) layout (for q,k)
// ---------------------------------------------------------------------------
__global__ __launch_bounds__(256)
void gemm_proj(const float* __restrict__ X, const float* __restrict__ W,
               const float* __restrict__ bias, float* __restrict__ outF,
               unsigned short* __restrict__ outHi, unsigned short* __restrict__ outLo,
               int mode)
{
  __shared__ float Xs[16][68];
  __shared__ float Ws[16][68];
  const int t  = threadIdx.x;
  const int nb = blockIdx.x & 15;
  const int mb = blockIdx.x >> 4;
  const int m0 = mb * 64, n0 = nb * 64;
  const int tx = t & 15, ty = t >> 4;
  const int lm = t >> 2;
  const int lk = (t & 3) * 4;
  const float* xsrc = X + (size_t)(m0 + lm) * 1024 + lk;
  const float* wsrc = W + (size_t)(n0 + lm) * 1024 + lk;

  float acc[4][4];
#pragma unroll
  for (int i = 0; i < 4; i++)
#pragma unroll
    for (int j = 0; j < 4; j++) acc[i][j] = 0.0f;

  for (int k0 = 0; k0 < 1024; k0 += 16) {
    float4 xv = *(const float4*)(xsrc + k0);
    float4 wv = *(const float4*)(wsrc + k0);
    __syncthreads();
    Xs[lk+0][lm] = xv.x; Xs[lk+1][lm] = xv.y; Xs[lk+2][lm] = xv.z; Xs[lk+3][lm] = xv.w;
    Ws[lk+0][lm] = wv.x; Ws[lk+1][lm] = wv.y; Ws[lk+2][lm] = wv.z; Ws[lk+3][lm] = wv.w;
    __syncthreads();
#pragma unroll
    for (int kk = 0; kk < 16; kk++) {
      float4 a = *(const float4*)&Xs[kk][ty*4];
      float4 b = *(const float4*)&Ws[kk][tx*4];
      acc[0][0] = fmaf(a.x, b.x, acc[0][0]);
      acc[0][1] = fmaf(a.x, b.y, acc[0][1]);
      acc[0][2] = fmaf(a.x, b.z, acc[0][2]);
      acc[0][3] = fmaf(a.x, b.w, acc[0][3]);
      acc[1][0] = fmaf(a.y, b.x, acc[1][0]);
      acc[1][1] = fmaf(a.y, b.y, acc[1][1]);
      acc[1][2] = fmaf(a.y, b.z, acc[1][2]);
      acc[1][3] = fmaf(a.y, b.w, acc[1][3]);
      acc[2][0] = fmaf(a.z, b.x, acc[2][0]);
      acc[2][1] = fmaf(a.z, b.y, acc[2][1]);
      acc[2][2] = fmaf(a.z, b.z, acc[2][2]);
      acc[2][3] = fmaf(a.z, b.w, acc[2][3]);
      acc[3][0] = fmaf(a.w, b.x, acc[3][0]);
      acc[3][1] = fmaf(a.w, b.y, acc[3][1]);
      acc[3][2] = fmaf(a.w, b.z, acc[3][2]);
      acc[3][3] = fmaf(a.w, b.w, acc[3][3]);
    }
  }

  float4 bv = *(const float4*)(bias + n0 + tx*4);
#pragma unroll
  for (int i = 0; i < 4; i++) {
    int m = m0 + ty*4 + i;
    float r0 = acc[i][0] + bv.x;
    float r1 = acc[i][1] + bv.y;
    float r2 = acc[i][2] + bv.z;
    float r3 = acc[i][3] + bv.w;
    if (mode == 2) {
      int bb = m >> 11, s = m & 2047;
      size_t off = ((size_t)(bb * NH + nb) * SEQ + s) * DKH + tx*4;
      float rr[4] = {r0, r1, r2, r3};
      ushort4 h, l;
      unsigned short hs[4], ls[4];
#pragma unroll
      for (int j = 0; j < 4; j++) {
        unsigned int u = __float_as_uint(rr[j]);
        hs[j] = (unsigned short)(u >> 16);
        float hf = __uint_as_float(u & 0xffff0000u);
        float lf = rr[j] - hf;
        ls[j] = (unsigned short)(__float_as_uint(lf) >> 16);
      }
      h.x = hs[0]; h.y = hs[1]; h.z = hs[2]; h.w = hs[3];
      l.x = ls[0]; l.y = ls[1]; l.z = ls[2]; l.w = ls[3];
      *(ushort4*)(outHi + off) = h;
      *(ushort4*)(outLo + off) = l;
    } else {
      size_t off;
      if (mode == 1) {
        int bb = m >> 11, s = m & 2047;
        off = ((size_t)(bb * NH + nb) * SEQ + s) * DKH + tx*4;
      } else {
        off = (size_t)m * 1024 + n0 + tx*4;
      }
      float4 r; r.x = r0; r.y = r1; r.z = r2; r.w = r3;
      *(float4*)(outF + off) = r;
    }
  }
}

// ---------------------------------------------------------------------------
// Attention: split-bf16 MFMA QK^T + exact causal top-64 + sparse PV.
// Block = 512 threads (8 waves) = 8 rows of one (b,h); ONE row per wave in
// phase 2 so keys[32] is register-resident (all loops statically unrolled).
// ---------------------------------------------------------------------------
struct AttnSmem {
  float scores[8][SEQ];                 // 64 KB, read-only after phase 1
  unsigned short lists[8][LIST_CAP];    // kept col indices (per row)
  float plist[8][LIST_CAP];             // kept p values (per row)
  float cand[8][64];
};

__global__ __launch_bounds__(512, 4)
void attn_topk(const unsigned short* __restrict__ qhi, const unsigned short* __restrict__ qlo,
               const unsigned short* __restrict__ khi, const unsigned short* __restrict__ klo,
               const float* __restrict__ vp, float* __restrict__ ao)
{
  __shared__ AttnSmem sm;
  const int t    = threadIdx.x;
  const int lane = t & 63;
  const int w    = t >> 6;            // 0..7
  const int bh   = blockIdx.x >> 8;
  const int rb   = blockIdx.x & 255;
  const int i0   = rb * 8;
  const size_t bhoff = (size_t)bh * SEQ * DKH;
  const unsigned short* qh = qhi + bhoff;
  const unsigned short* ql = qlo + bhoff;
  const unsigned short* kh = khi + bhoff;
  const unsigned short* kl = klo + bhoff;
  const float* vbase = vp + bhoff;

  // ---- phase 1: MFMA QK^T into LDS scores (split-bf16 3-pass) ----
  const int am   = lane & 15;
  const int aq   = lane >> 4;
  const int dofs = aq * 8;

  short8 a_hi[2], a_lo[2];
#pragma unroll
  for (int c = 0; c < 2; c++) {
    size_t off = (size_t)(i0 + am) * DKH + c*32 + dofs;  // rows 8..15 over-read land in next plane
    a_hi[c] = *(const short8*)(qh + off);
    a_lo[c] = *(const short8*)(ql + off);
  }

  const int T = (i0 >> 4) + 1;
  short8 b_hi[2], b_lo[2];
  int tt = w;
  if (tt < T) {
#pragma unroll
    for (int c = 0; c < 2; c++) {
      size_t off = (size_t)(tt*16 + am) * DKH + c*32 + dofs;
      b_hi[c] = *(const short8*)(kh + off);
      b_lo[c] = *(const short8*)(kl + off);
    }
  }
  for (; tt < T; tt += 8) {
    short8 n_hi[2], n_lo[2];
    const int tn = tt + 8;
    if (tn < T) {
#pragma unroll
      for (int c = 0; c < 2; c++) {
        size_t off = (size_t)(tn*16 + am) * DKH + c*32 + dofs;
        n_hi[c] = *(const short8*)(kh + off);
        n_lo[c] = *(const short8*)(kl + off);
      }
    } else {
#pragma unroll
      for (int c = 0; c < 2; c++) { n_hi[c] = b_hi[c]; n_lo[c] = b_lo[c]; }
    }
    f32x4 C = {0.0f, 0.0f, 0.0f, 0.0f};
#pragma unroll
    for (int c = 0; c < 2; c++) {
      C = __builtin_amdgcn_mfma_f32_16x16x32_bf16(a_hi[c], b_hi[c], C, 0, 0, 0);
      C = __builtin_amdgcn_mfma_f32_16x16x32_bf16(a_lo[c], b_hi[c], C, 0, 0, 0);
      C = __builtin_amdgcn_mfma_f32_16x16x32_bf16(a_hi[c], b_lo[c], C, 0, 0, 0);
    }
    if (aq < 2) {
      const int j = tt*16 + am;
#pragma unroll
      for (int reg = 0; reg < 4; reg++) {
        const int rr = aq*4 + reg;
        sm.scores[rr][j] = (j <= i0 + rr) ? C[reg] * 0.125f : NEGV;
      }
    }
#pragma unroll
    for (int c = 0; c < 2; c++) { b_hi[c] = n_hi[c]; b_lo[c] = n_lo[c]; }
  }
  __syncthreads();

  // ---- phase 2: one row per wave; keys register-resident (static unrolls) ----
  const int bb = bh >> 4, hh = bh & 15;
  const int r = w;
  const int i = i0 + w;

  unsigned int keys[32];
  float vmax = NEGV, vmin = 3.4e38f;
#pragma unroll
  for (int u2 = 0; u2 < 32; u2++) {
    const int j = lane + 64*u2;
    float v = NEGV;
    if (j <= i) v = sm.scores[r][j];
    vmax = fmaxf(vmax, v);
    if (v > -5000.0f) vmin = fminf(vmin, v);
    keys[u2] = f2k(v);
  }
#pragma unroll
  for (int off = 32; off; off >>= 1) {
    vmax = fmaxf(vmax, __shfl_xor(vmax, off));
    vmin = fminf(vmin, __shfl_xor(vmin, off));
  }

  float vk;
  if (i + 1 <= 64) {
    vk = NEGV;                        // <=64 valid: keep all
  } else {
    unsigned int ka = f2k(vmin);      // count(>=ka) = i+1 >= 65
    unsigned int kb = f2k(vmax) + 1u; // count(>=kb) = 0
    int ca = i + 1, cb = 0;
    int guard = 0;
    while (kb - ka > 1u && (ca - cb) > 56 && guard < 64) {
      guard++;
      float fm = 0.5f * (k2f(ka) + k2f(kb));
      unsigned int km = f2k(fm);
      if (km <= ka || km >= kb) km = ka + ((kb - ka) >> 1);
      int cnt = 0;
#pragma unroll
      for (int u2 = 0; u2 < 32; u2++) cnt += (keys[u2] >= km) ? 1 : 0;
#pragma unroll
      for (int off = 32; off; off >>= 1) cnt += __shfl_xor(cnt, off);
      if (cnt >= 64) { ka = km; ca = cnt; } else { kb = km; cb = cnt; }
    }
    if (kb - ka == 1u || (ca - cb) > 64) {
      vk = k2f(ka);                   // interval collapsed (dups) -> exact
    } else {
      // gather candidates in [ka,kb) via ballot compaction (no atomics)
      int cbase = 0;
#pragma unroll
      for (int u2 = 0; u2 < 32; u2++) {
        unsigned int kx = keys[u2];
        bool in = (kx >= ka && kx < kb);
        unsigned long long mask = __ballot(in);
        if (in) sm.cand[w][cbase + lanecnt_lt(mask)] = k2f(kx);
        cbase += __popcll(mask);
      }
      const int nc = cbase;           // <= 64 guaranteed on this path
      float cv = (lane < nc) ? sm.cand[w][lane] : -3.4e38f;
      for (int ks = 2; ks <= 64; ks <<= 1) {
        for (int j2 = ks >> 1; j2 > 0; j2 >>= 1) {
          float other = __shfl_xor(cv, j2);
          bool up    = ((lane & ks) == 0);
          bool lower = ((lane & j2) == 0);
          float mn = fminf(cv, other), mx = fmaxf(cv, other);
          cv = (up == lower) ? mn : mx;
        }
      }
      int need = 64 - cb;
      vk = __shfl(cv, 64 - need);
    }
  }

  // softmax (p = s>=vk ? exp(s-max) : 0) + compact (j,p) kept list
  float z = 0.0f;
  int base = 0;
#pragma unroll
  for (int u2 = 0; u2 < 32; u2++) {
    const int j = lane + 64*u2;
    float sv = k2f(keys[u2]);
    float p = (sv >= vk) ? __expf(sv - vmax) : 0.0f;   // NEG entries underflow to 0
    z += p;
    unsigned long long mask = __ballot(p > 0.0f);
    if (p > 0.0f) {
      int pos = base + lanecnt_lt(mask);
      if (pos < LIST_CAP) { sm.lists[r][pos] = (unsigned short)j; sm.plist[r][pos] = p; }
    }
    base += __popcll(mask);
  }
#pragma unroll
  for (int off = 32; off; off >>= 1) z += __shfl_xor(z, off);
  const float rz = 1.0f / z;

  // sparse PV: lane = head dim; 8 V-row loads in flight
  float acc = 0.0f;
  if (base <= LIST_CAP) {
    int u = 0;
    for (; u + 8 <= base; u += 8) {
      int   jj[8]; float pp[8]; float vv[8];
#pragma unroll
      for (int q2 = 0; q2 < 8; q2++) { jj[q2] = sm.lists[r][u+q2]; pp[q2] = sm.plist[r][u+q2]; }
#pragma unroll
      for (int q2 = 0; q2 < 8; q2++) vv[q2] = vbase[(size_t)jj[q2] * DKH + lane];
#pragma unroll
      for (int q2 = 0; q2 < 8; q2++) acc = fmaf(pp[q2], vv[q2], acc);
    }
    for (; u < base; u++)
      acc = fmaf(sm.plist[r][u], vbase[(size_t)sm.lists[r][u] * DKH + lane], acc);
  } else {                            // ties pathology: dense recompute (scores intact)
    for (int jx = 0; jx <= i; jx++) {
      float sv = sm.scores[r][jx];
      float p = (sv >= vk) ? __expf(sv - vmax) : 0.0f;
      acc = fmaf(p, vbase[(size_t)jx * DKH + lane], acc);
    }
  }
  ao[((size_t)(bb * SEQ + i) * NH + hh) * DKH + lane] = acc * rz;
}

// ---------------------------------------------------------------------------
extern "C" void kernel_launch(void* const* d_in, const int* in_sizes, int n_in,
                              void* d_out, int out_size, void* d_ws, size_t ws_size,
                              hipStream_t stream)
{
  const float* query = (const float*)d_in[0];
  const float* key   = (const float*)d_in[1];
  const float* value = (const float*)d_in[2];
  const float* Wq    = (const float*)d_in[3];
  const float* bq    = (const float*)d_in[4];
  const float* Wk    = (const float*)d_in[5];
  const float* bk    = (const float*)d_in[6];
  const float* Wv    = (const float*)d_in[7];
  const float* bv    = (const float*)d_in[8];
  const float* Wo    = (const float*)d_in[9];
  const float* bo    = (const float*)d_in[10];

  // ws (64 MB): q_hi(8) q_lo(8) k_hi(8) k_lo(8) v_f32(16) ao_f32(16)
  const size_t NE = (size_t)4194304;   // B*H*S*DK
  unsigned short* q_hi = (unsigned short*)d_ws;
  unsigned short* q_lo = q_hi + NE;
  unsigned short* k_hi = q_lo + NE;
  unsigned short* k_lo = k_hi + NE;
  float* vpf = (float*)(k_lo + NE);
  float* aop = vpf + NE;
  float* out = (float*)d_out;

  hipLaunchKernelGGL(gemm_proj, dim3(1024), dim3(256), 0, stream, query, Wq, bq, (float*)nullptr, q_hi, q_lo, 2);
  hipLaunchKernelGGL(gemm_proj, dim3(1024), dim3(256), 0, stream, key,   Wk, bk, (float*)nullptr, k_hi, k_lo, 2);
  hipLaunchKernelGGL(gemm_proj, dim3(1024), dim3(256), 0, stream, value, Wv, bv, vpf, (unsigned short*)nullptr, (unsigned short*)nullptr, 1);
  hipLaunchKernelGGL(attn_topk, dim3(8192), dim3(512), 0, stream, q_hi, q_lo, k_hi, k_lo, vpf, aop);
  hipLaunchKernelGGL(gemm_proj, dim3(1024), dim3(256), 0, stream, aop, Wo, bo, out, (unsigned short*)nullptr, (unsigned short*)nullptr, 0);
}

// Round 4
// 778.319 us; speedup vs baseline: 1.8738x; 1.3237x over previous
//
#include <hip/hip_runtime.h>
#include <hip/hip_bf16.h>
#include <math.h>

#define SEQ 2048
#define DKH 64
#define NH 16
#define NEGV -10000.0f
#define LIST_CAP 160

typedef __attribute__((ext_vector_type(8))) short short8;
typedef __attribute__((ext_vector_type(4))) float f32x4;

__device__ __forceinline__ unsigned int f2k(float f) {
  unsigned int u = __float_as_uint(f);
  return (u & 0x80000000u) ? ~u : (u | 0x80000000u);
}
__device__ __forceinline__ float k2f(unsigned int k) {
  unsigned int u = (k & 0x80000000u) ? (k & 0x7FFFFFFFu) : ~k;
  return __uint_as_float(u);
}
__device__ __forceinline__ int lanecnt_lt(unsigned long long m) {
  return __builtin_amdgcn_mbcnt_hi((unsigned int)(m >> 32),
         __builtin_amdgcn_mbcnt_lo((unsigned int)m, 0));
}
__device__ __forceinline__ void split_hl(float x, unsigned short* h, unsigned short* l) {
  unsigned int u = __float_as_uint(x);
  *h = (unsigned short)(u >> 16);
  float hf = __uint_as_float(u & 0xffff0000u);
  *l = (unsigned short)(__float_as_uint(x - hf) >> 16);
}
__device__ __forceinline__ void glds16(const unsigned short* g, unsigned short* l) {
  __builtin_amdgcn_global_load_lds(
      (const __attribute__((address_space(1))) unsigned int*)g,
      (__attribute__((address_space(3))) unsigned int*)l, 16, 0, 0);
}

// ---------------------------------------------------------------------------
// fp32 -> [hi(1024) | lo(1024)] bf16 planes, row-major M x 2048 ushort.
// ---------------------------------------------------------------------------
__global__ __launch_bounds__(256)
void conv_xhl(const float* __restrict__ X, unsigned short* __restrict__ O)
{
  int idx = blockIdx.x * 256 + threadIdx.x;   // one thread per 4 elements
  int m = idx >> 8;
  int c = (idx & 255) * 4;
  float4 v = *(const float4*)(X + (size_t)m * 1024 + c);
  float xs[4] = {v.x, v.y, v.z, v.w};
  ushort4 h, l;
  unsigned short hh[4], ll[4];
#pragma unroll
  for (int q = 0; q < 4; q++) split_hl(xs[q], &hh[q], &ll[q]);
  h.x=hh[0]; h.y=hh[1]; h.z=hh[2]; h.w=hh[3];
  l.x=ll[0]; l.y=ll[1]; l.z=ll[2]; l.w=ll[3];
  *(ushort4*)(O + (size_t)m * 2048 + c) = h;
  *(ushort4*)(O + (size_t)m * 2048 + 1024 + c) = l;
}

// Same for weights (1024 x 1024 fp32 -> 1024 x 2048 hl).
__global__ __launch_bounds__(256)
void conv_whl(const float* __restrict__ W, unsigned short* __restrict__ O)
{
  int idx = blockIdx.x * 256 + threadIdx.x;
  int n = idx >> 8;
  int c = (idx & 255) * 4;
  float4 v = *(const float4*)(W + (size_t)n * 1024 + c);
  float xs[4] = {v.x, v.y, v.z, v.w};
  ushort4 h, l;
  unsigned short hh[4], ll[4];
#pragma unroll
  for (int q = 0; q < 4; q++) split_hl(xs[q], &hh[q], &ll[q]);
  h.x=hh[0]; h.y=hh[1]; h.z=hh[2]; h.w=hh[3];
  l.x=ll[0]; l.y=ll[1]; l.z=ll[2]; l.w=ll[3];
  *(ushort4*)(O + (size_t)n * 2048 + c) = h;
  *(ushort4*)(O + (size_t)n * 2048 + 1024 + c) = l;
}

// ---------------------------------------------------------------------------
// Split-bf16 MFMA GEMM: C[m,n] = sum_c X[m,c]*W[n,c] + bias[n] computed as
// Xhi*Whi + Xhi*Wlo + Xlo*Whi via a single ext-K loop (Kext=3072):
//   kext<1024: A hi, B hi; 1024..2047: A hi, B lo; 2048..: A lo, B hi.
// A: M x 2048 hl, B: N x 2048 hl. Tile 128(M) x 64(N), BK=64, 256 thr.
// Grid 32 x 16 = 512 blocks (2/CU). Epilogue modes:
//   0: outF[m][n] fp32        1: outHL bhsd hl (q,k)     2: outBH bhsd fp32 (v)
// ---------------------------------------------------------------------------
__global__ __launch_bounds__(256)
void gemm_mfma(const unsigned short* __restrict__ A,
               const unsigned short* __restrict__ Bw,
               const float* __restrict__ bias,
               float* __restrict__ outF,
               unsigned short* __restrict__ outHL,
               float* __restrict__ outBH,
               int mode)
{
  __shared__ unsigned short As[128 * 64];
  __shared__ unsigned short Bs[64 * 64];
  const int t = threadIdx.x, lane = t & 63, w = t >> 6;
  const int nb = blockIdx.x & 15, mb = blockIdx.x >> 4;
  const int m0 = mb * 128, n0 = nb * 64;
  const int am = lane & 15, aq = lane >> 4;
  const int wr = w >> 1, wc = w & 1;
  const int srow = lane >> 3;
  const int scol = (lane & 7) * 8;

  f32x4 acc[4][2];
#pragma unroll
  for (int mt = 0; mt < 4; mt++)
#pragma unroll
    for (int nt = 0; nt < 2; nt++) acc[mt][nt] = (f32x4){0.f, 0.f, 0.f, 0.f};

  for (int kx = 0; kx < 3072; kx += 64) {
    const int acol = (kx < 1024) ? kx : kx - 1024;   // hi, hi, lo
    const int bcol = (kx < 2048) ? kx : kx - 2048;   // hi, lo, hi
    __syncthreads();
#pragma unroll
    for (int ch = 0; ch < 4; ch++) {                 // A: 128 rows, 4 chunks/wave
      int row = w * 32 + ch * 8 + srow;
      glds16(A + (size_t)(m0 + row) * 2048 + acol + scol,
             &As[(w * 32 + ch * 8) * 64 + lane * 8]);
    }
#pragma unroll
    for (int ch = 0; ch < 2; ch++) {                 // B: 64 rows, 2 chunks/wave
      int row = w * 16 + ch * 8 + srow;
      glds16(Bw + (size_t)(n0 + row) * 2048 + bcol + scol,
             &Bs[(w * 16 + ch * 8) * 64 + lane * 8]);
    }
    __syncthreads();

    short8 af[4][2], bf[2][2];
#pragma unroll
    for (int kk = 0; kk < 2; kk++) {
#pragma unroll
      for (int mt = 0; mt < 4; mt++)
        af[mt][kk] = *(const short8*)&As[(wr * 64 + mt * 16 + am) * 64 + kk * 32 + aq * 8];
#pragma unroll
      for (int nt = 0; nt < 2; nt++)
        bf[nt][kk] = *(const short8*)&Bs[(wc * 32 + nt * 16 + am) * 64 + kk * 32 + aq * 8];
    }
#pragma unroll
    for (int kk = 0; kk < 2; kk++)
#pragma unroll
      for (int mt = 0; mt < 4; mt++)
#pragma unroll
        for (int nt = 0; nt < 2; nt++)
          acc[mt][nt] = __builtin_amdgcn_mfma_f32_16x16x32_bf16(af[mt][kk], bf[nt][kk], acc[mt][nt], 0, 0, 0);
  }

#pragma unroll
  for (int mt = 0; mt < 4; mt++)
#pragma unroll
    for (int nt = 0; nt < 2; nt++)
#pragma unroll
      for (int reg = 0; reg < 4; reg++) {
        const int gm = m0 + wr * 64 + mt * 16 + aq * 4 + reg;
        const int gn = n0 + wc * 32 + nt * 16 + am;
        float val = acc[mt][nt][reg] + bias[gn];
        if (mode == 0) {
          outF[(size_t)gm * 1024 + gn] = val;
        } else {
          const int bb = gm >> 11, s = gm & 2047, h2 = gn >> 6, d = gn & 63;
          const size_t row = ((size_t)(bb * NH + h2)) * SEQ + s;
          if (mode == 2) {
            outBH[row * DKH + d] = val;
          } else {
            unsigned short h, l;
            split_hl(val, &h, &l);
            outHL[row * 128 + d] = h;
            outHL[row * 128 + 64 + d] = l;
          }
        }
      }
}

// ---------------------------------------------------------------------------
// Attention: split-bf16 MFMA QK^T + exact causal top-64 + sparse PV.
// q/k in bhsd hl layout (row stride 128 ushorts: hi|lo). V fp32 bhsd.
// Output written directly as hl planes (M x 2048) for the final GEMM.
// ---------------------------------------------------------------------------
struct AttnSmem {
  float scores[8][SEQ];                 // 64 KB, raw scores (kept for fallback)
  unsigned short lists[8][LIST_CAP];
  float plist[8][LIST_CAP];
  float cand[8][64];
};

__global__ __launch_bounds__(512, 4)
void attn_topk(const unsigned short* __restrict__ qhl, const unsigned short* __restrict__ khl,
               const float* __restrict__ vp, unsigned short* __restrict__ aohl)
{
  __shared__ AttnSmem sm;
  const int t    = threadIdx.x;
  const int lane = t & 63;
  const int w    = t >> 6;            // 0..7
  const int bh   = blockIdx.x >> 8;
  const int rb   = blockIdx.x & 255;
  const int i0   = rb * 8;
  const unsigned short* qb = qhl + (size_t)bh * SEQ * 128;
  const unsigned short* kb = khl + (size_t)bh * SEQ * 128;
  const float* vbase = vp + (size_t)bh * SEQ * DKH;

  // ---- phase 1: MFMA QK^T into LDS scores (3-term split-bf16) ----
  const int am   = lane & 15;
  const int aq   = lane >> 4;
  const int dofs = aq * 8;

  short8 a_hi[2], a_lo[2];
#pragma unroll
  for (int c = 0; c < 2; c++) {
    size_t off = (size_t)(i0 + am) * 128 + c * 32 + dofs;  // rows 8..15 over-read -> next buffer, discarded
    a_hi[c] = *(const short8*)(qb + off);
    a_lo[c] = *(const short8*)(qb + off + 64);
  }

  const int T = (i0 >> 4) + 1;
  short8 b_hi[2], b_lo[2];
  int tt = w;
  if (tt < T) {
#pragma unroll
    for (int c = 0; c < 2; c++) {
      size_t off = (size_t)(tt * 16 + am) * 128 + c * 32 + dofs;
      b_hi[c] = *(const short8*)(kb + off);
      b_lo[c] = *(const short8*)(kb + off + 64);
    }
  }
  for (; tt < T; tt += 8) {
    short8 n_hi[2], n_lo[2];
    const int tn = tt + 8;
    if (tn < T) {
#pragma unroll
      for (int c = 0; c < 2; c++) {
        size_t off = (size_t)(tn * 16 + am) * 128 + c * 32 + dofs;
        n_hi[c] = *(const short8*)(kb + off);
        n_lo[c] = *(const short8*)(kb + off + 64);
      }
    } else {
#pragma unroll
      for (int c = 0; c < 2; c++) { n_hi[c] = b_hi[c]; n_lo[c] = b_lo[c]; }
    }
    f32x4 C = {0.0f, 0.0f, 0.0f, 0.0f};
#pragma unroll
    for (int c = 0; c < 2; c++) {
      C = __builtin_amdgcn_mfma_f32_16x16x32_bf16(a_hi[c], b_hi[c], C, 0, 0, 0);
      C = __builtin_amdgcn_mfma_f32_16x16x32_bf16(a_lo[c], b_hi[c], C, 0, 0, 0);
      C = __builtin_amdgcn_mfma_f32_16x16x32_bf16(a_hi[c], b_lo[c], C, 0, 0, 0);
    }
    if (aq < 2) {
      const int j = tt * 16 + am;
#pragma unroll
      for (int reg = 0; reg < 4; reg++) {
        const int rr = aq * 4 + reg;
        sm.scores[rr][j] = (j <= i0 + rr) ? C[reg] * 0.125f : NEGV;
      }
    }
#pragma unroll
    for (int c = 0; c < 2; c++) { b_hi[c] = n_hi[c]; b_lo[c] = n_lo[c]; }
  }
  __syncthreads();

  // ---- phase 2: one row per wave; keys register-resident ----
  const int bb = bh >> 4, hh = bh & 15;
  const int r = w;
  const int i = i0 + w;
  const int sbmax = i >> 8;            // valid 256-col super-blocks

  unsigned int keys[32];
#pragma unroll
  for (int u = 0; u < 32; u++) keys[u] = f2k(NEGV);
  float vmax = NEGV, vmin = 3.4e38f;
#pragma unroll
  for (int sb = 0; sb < 8; sb++) {
    if (sb <= sbmax) {                 // wave-uniform guard (no break -> regs)
      float4 vv = *(const float4*)&sm.scores[r][sb * 256 + lane * 4];
      float e[4] = {vv.x, vv.y, vv.z, vv.w};
#pragma unroll
      for (int q = 0; q < 4; q++) {
        const int j = sb * 256 + lane * 4 + q;
        float v = (j <= i) ? e[q] : NEGV;
        vmax = fmaxf(vmax, v);
        if (v > -5000.0f) vmin = fminf(vmin, v);
        keys[sb * 4 + q] = f2k(v);
      }
    }
  }
#pragma unroll
  for (int off = 32; off; off >>= 1) {
    vmax = fmaxf(vmax, __shfl_xor(vmax, off));
    vmin = fminf(vmin, __shfl_xor(vmin, off));
  }

  float vk;
  if (i + 1 <= 64) {
    vk = NEGV;
  } else {
    unsigned int ka = f2k(vmin);
    unsigned int kb2 = f2k(vmax) + 1u;
    int ca = i + 1, cb = 0;
    int guard = 0;
    while (kb2 - ka > 1u && (ca - cb) > 56 && guard < 64) {
      guard++;
      float fm = 0.5f * (k2f(ka) + k2f(kb2));
      unsigned int km = f2k(fm);
      if (km <= ka || km >= kb2) km = ka + ((kb2 - ka) >> 1);
      int cnt = 0;
#pragma unroll
      for (int u = 0; u < 32; u++)
        cnt += __popcll(__ballot(keys[u] >= km));   // v_cmp + scalar bcnt
      if (cnt >= 64) { ka = km; ca = cnt; } else { kb2 = km; cb = cnt; }
    }
    if (kb2 - ka == 1u || (ca - cb) > 64) {
      vk = k2f(ka);
    } else {
      int cbase = 0;
#pragma unroll
      for (int u = 0; u < 32; u++) {
        unsigned int kx = keys[u];
        bool in = (kx >= ka && kx < kb2);
        unsigned long long mask = __ballot(in);
        if (in) sm.cand[w][cbase + lanecnt_lt(mask)] = k2f(kx);
        cbase += __popcll(mask);
      }
      const int nc = cbase;
      float cv = (lane < nc) ? sm.cand[w][lane] : -3.4e38f;
      for (int ks = 2; ks <= 64; ks <<= 1) {
        for (int j2 = ks >> 1; j2 > 0; j2 >>= 1) {
          float other = __shfl_xor(cv, j2);
          bool up    = ((lane & ks) == 0);
          bool lower = ((lane & j2) == 0);
          float mn = fminf(cv, other), mx = fmaxf(cv, other);
          cv = (up == lower) ? mn : mx;
        }
      }
      int need = 64 - cb;
      vk = __shfl(cv, 64 - need);
    }
  }

  // softmax + compact (j,p) kept list
  float z = 0.0f;
  int base = 0;
#pragma unroll
  for (int u = 0; u < 32; u++) {
    if ((u >> 2) <= sbmax) {           // wave-uniform guard
      const int j = (u >> 2) * 256 + lane * 4 + (u & 3);
      float sv = k2f(keys[u]);
      float p = (sv >= vk) ? __expf(sv - vmax) : 0.0f;
      z += p;
      unsigned long long mask = __ballot(p > 0.0f);
      if (p > 0.0f) {
        int pos = base + lanecnt_lt(mask);
        if (pos < LIST_CAP) { sm.lists[r][pos] = (unsigned short)j; sm.plist[r][pos] = p; }
      }
      base += __popcll(mask);
    }
  }
#pragma unroll
  for (int off = 32; off; off >>= 1) z += __shfl_xor(z, off);
  const float rz = 1.0f / z;

  // sparse PV: lane = head dim; 8 V-row loads in flight
  float acc = 0.0f;
  if (base <= LIST_CAP) {
    int u = 0;
    for (; u + 8 <= base; u += 8) {
      int jj[8]; float pp[8]; float vv[8];
#pragma unroll
      for (int q2 = 0; q2 < 8; q2++) { jj[q2] = sm.lists[r][u+q2]; pp[q2] = sm.plist[r][u+q2]; }
#pragma unroll
      for (int q2 = 0; q2 < 8; q2++) vv[q2] = vbase[(size_t)jj[q2] * DKH + lane];
#pragma unroll
      for (int q2 = 0; q2 < 8; q2++) acc = fmaf(pp[q2], vv[q2], acc);
    }
    for (; u < base; u++)
      acc = fmaf(sm.plist[r][u], vbase[(size_t)sm.lists[r][u] * DKH + lane], acc);
  } else {
    for (int jx = 0; jx <= i; jx++) {
      float sv = sm.scores[r][jx];
      float p = (sv >= vk) ? __expf(sv - vmax) : 0.0f;
      acc = fmaf(p, vbase[(size_t)jx * DKH + lane], acc);
    }
  }

  // epilogue: write ao as hl planes (row-major M x 2048) for the final GEMM
  float val = acc * rz;
  unsigned short h, l;
  split_hl(val, &h, &l);
  const size_t arow = (size_t)(bb * SEQ + i) * 2048;
  aohl[arow + hh * 64 + lane] = h;
  aohl[arow + 1024 + hh * 64 + lane] = l;
}

// ---------------------------------------------------------------------------
extern "C" void kernel_launch(void* const* d_in, const int* in_sizes, int n_in,
                              void* d_out, int out_size, void* d_ws, size_t ws_size,
                              hipStream_t stream)
{
  const float* query = (const float*)d_in[0];
  const float* key   = (const float*)d_in[1];
  const float* value = (const float*)d_in[2];
  const float* Wq    = (const float*)d_in[3];
  const float* bq    = (const float*)d_in[4];
  const float* Wk    = (const float*)d_in[5];
  const float* bk    = (const float*)d_in[6];
  const float* Wv    = (const float*)d_in[7];
  const float* bv    = (const float*)d_in[8];
  const float* Wo    = (const float*)d_in[9];
  const float* bo    = (const float*)d_in[10];

  // ws (54.5 MB): xhl(16) | whl(4) | qhl(16) | khl(16). V fp32 lives in d_out
  // (scratch until the final GEMM overwrites it).
  unsigned short* xhl = (unsigned short*)d_ws;            // 4096 x 2048
  unsigned short* whl = xhl + (size_t)4096 * 2048;        // 1024 x 2048
  unsigned short* qhl = whl + (size_t)1024 * 2048;        // 65536 x 128 (bhsd hl)
  unsigned short* khl = qhl + (size_t)65536 * 128;
  float* vpf = (float*)d_out;                             // 65536 x 64 fp32 (bhsd)

  hipLaunchKernelGGL(conv_xhl, dim3(4096), dim3(256), 0, stream, query, xhl);
  hipLaunchKernelGGL(conv_whl, dim3(1024), dim3(256), 0, stream, Wq, whl);
  hipLaunchKernelGGL(gemm_mfma, dim3(512), dim3(256), 0, stream, xhl, whl, bq,
                     (float*)nullptr, qhl, (float*)nullptr, 1);
  hipLaunchKernelGGL(conv_xhl, dim3(4096), dim3(256), 0, stream, key, xhl);
  hipLaunchKernelGGL(conv_whl, dim3(1024), dim3(256), 0, stream, Wk, whl);
  hipLaunchKernelGGL(gemm_mfma, dim3(512), dim3(256), 0, stream, xhl, whl, bk,
                     (float*)nullptr, khl, (float*)nullptr, 1);
  hipLaunchKernelGGL(conv_xhl, dim3(4096), dim3(256), 0, stream, value, xhl);
  hipLaunchKernelGGL(conv_whl, dim3(1024), dim3(256), 0, stream, Wv, whl);
  hipLaunchKernelGGL(gemm_mfma, dim3(512), dim3(256), 0, stream, xhl, whl, bv,
                     (float*)nullptr, (unsigned short*)nullptr, vpf, 2);
  hipLaunchKernelGGL(attn_topk, dim3(8192), dim3(512), 0, stream, qhl, khl, vpf, xhl);
  hipLaunchKernelGGL(conv_whl, dim3(1024), dim3(256), 0, stream, Wo, whl);
  hipLaunchKernelGGL(gemm_mfma, dim3(512), dim3(256), 0, stream, xhl, whl, bo,
                     (float*)d_out, (unsigned short*)nullptr, (float*)nullptr, 0);
}

// Round 5
// 773.490 us; speedup vs baseline: 1.8855x; 1.0062x over previous
//
#include <hip/hip_runtime.h>
#include <hip/hip_bf16.h>
#include <math.h>

#define SEQ 2048
#define DKH 64
#define NH 16
#define NEGV -10000.0f
#define LIST_CAP 160

typedef __attribute__((ext_vector_type(8))) short short8;
typedef __attribute__((ext_vector_type(4))) float f32x4;

__device__ __forceinline__ unsigned int f2k(float f) {
  unsigned int u = __float_as_uint(f);
  return (u & 0x80000000u) ? ~u : (u | 0x80000000u);
}
__device__ __forceinline__ float k2f(unsigned int k) {
  unsigned int u = (k & 0x80000000u) ? (k & 0x7FFFFFFFu) : ~k;
  return __uint_as_float(u);
}
__device__ __forceinline__ int lanecnt_lt(unsigned long long m) {
  return __builtin_amdgcn_mbcnt_hi((unsigned int)(m >> 32),
         __builtin_amdgcn_mbcnt_lo((unsigned int)m, 0));
}
__device__ __forceinline__ void split_hl(float x, unsigned short* h, unsigned short* l) {
  unsigned int u = __float_as_uint(x);
  *h = (unsigned short)(u >> 16);
  float hf = __uint_as_float(u & 0xffff0000u);
  *l = (unsigned short)(__float_as_uint(x - hf) >> 16);
}
__device__ __forceinline__ void glds16(const unsigned short* g, unsigned short* l) {
  __builtin_amdgcn_global_load_lds(
      (const __attribute__((address_space(1))) unsigned int*)g,
      (__attribute__((address_space(3))) unsigned int*)l, 16, 0, 0);
}

// ---------------------------------------------------------------------------
// fp32 -> [hi(1024) | lo(1024)] bf16 planes, row-major M x 2048 ushort.
// ---------------------------------------------------------------------------
__global__ __launch_bounds__(256)
void conv_xhl(const float* __restrict__ X, unsigned short* __restrict__ O)
{
  int idx = blockIdx.x * 256 + threadIdx.x;   // one thread per 4 elements
  int m = idx >> 8;
  int c = (idx & 255) * 4;
  float4 v = *(const float4*)(X + (size_t)m * 1024 + c);
  float xs[4] = {v.x, v.y, v.z, v.w};
  ushort4 h, l;
  unsigned short hh[4], ll[4];
#pragma unroll
  for (int q = 0; q < 4; q++) split_hl(xs[q], &hh[q], &ll[q]);
  h.x=hh[0]; h.y=hh[1]; h.z=hh[2]; h.w=hh[3];
  l.x=ll[0]; l.y=ll[1]; l.z=ll[2]; l.w=ll[3];
  *(ushort4*)(O + (size_t)m * 2048 + c) = h;
  *(ushort4*)(O + (size_t)m * 2048 + 1024 + c) = l;
}

// Same for weights (1024 x 1024 fp32 -> 1024 x 2048 hl).
__global__ __launch_bounds__(256)
void conv_whl(const float* __restrict__ W, unsigned short* __restrict__ O)
{
  int idx = blockIdx.x * 256 + threadIdx.x;
  int n = idx >> 8;
  int c = (idx & 255) * 4;
  float4 v = *(const float4*)(W + (size_t)n * 1024 + c);
  float xs[4] = {v.x, v.y, v.z, v.w};
  ushort4 h, l;
  unsigned short hh[4], ll[4];
#pragma unroll
  for (int q = 0; q < 4; q++) split_hl(xs[q], &hh[q], &ll[q]);
  h.x=hh[0]; h.y=hh[1]; h.z=hh[2]; h.w=hh[3];
  l.x=ll[0]; l.y=ll[1]; l.z=ll[2]; l.w=ll[3];
  *(ushort4*)(O + (size_t)n * 2048 + c) = h;
  *(ushort4*)(O + (size_t)n * 2048 + 1024 + c) = l;
}

// ---------------------------------------------------------------------------
// Split-bf16 MFMA GEMM: C[m,n] = sum_c X[m,c]*W[n,c] + bias[n] computed as
// Xhi*Whi + Xhi*Wlo + Xlo*Whi via a single ext-K loop (Kext=3072).
// A: M x 2048 hl, B: N x 2048 hl. Tile 128(M) x 64(N), BK=64, 256 thr.
// Epilogue modes: 0 fp32 [m][n]; 1 bhsd hl (q,k); 2 bhsd fp32 (v).
// ---------------------------------------------------------------------------
__global__ __launch_bounds__(256)
void gemm_mfma(const unsigned short* __restrict__ A,
               const unsigned short* __restrict__ Bw,
               const float* __restrict__ bias,
               float* __restrict__ outF,
               unsigned short* __restrict__ outHL,
               float* __restrict__ outBH,
               int mode)
{
  __shared__ unsigned short As[128 * 64];
  __shared__ unsigned short Bs[64 * 64];
  const int t = threadIdx.x, lane = t & 63, w = t >> 6;
  const int nb = blockIdx.x & 15, mb = blockIdx.x >> 4;
  const int m0 = mb * 128, n0 = nb * 64;
  const int am = lane & 15, aq = lane >> 4;
  const int wr = w >> 1, wc = w & 1;
  const int srow = lane >> 3;
  const int scol = (lane & 7) * 8;

  f32x4 acc[4][2];
#pragma unroll
  for (int mt = 0; mt < 4; mt++)
#pragma unroll
    for (int nt = 0; nt < 2; nt++) acc[mt][nt] = (f32x4){0.f, 0.f, 0.f, 0.f};

  for (int kx = 0; kx < 3072; kx += 64) {
    const int acol = (kx < 1024) ? kx : kx - 1024;   // hi, hi, lo
    const int bcol = (kx < 2048) ? kx : kx - 2048;   // hi, lo, hi
    __syncthreads();
#pragma unroll
    for (int ch = 0; ch < 4; ch++) {                 // A: 128 rows, 4 chunks/wave
      int row = w * 32 + ch * 8 + srow;
      glds16(A + (size_t)(m0 + row) * 2048 + acol + scol,
             &As[(w * 32 + ch * 8) * 64 + lane * 8]);
    }
#pragma unroll
    for (int ch = 0; ch < 2; ch++) {                 // B: 64 rows, 2 chunks/wave
      int row = w * 16 + ch * 8 + srow;
      glds16(Bw + (size_t)(n0 + row) * 2048 + bcol + scol,
             &Bs[(w * 16 + ch * 8) * 64 + lane * 8]);
    }
    __syncthreads();

    short8 af[4][2], bf[2][2];
#pragma unroll
    for (int kk = 0; kk < 2; kk++) {
#pragma unroll
      for (int mt = 0; mt < 4; mt++)
        af[mt][kk] = *(const short8*)&As[(wr * 64 + mt * 16 + am) * 64 + kk * 32 + aq * 8];
#pragma unroll
      for (int nt = 0; nt < 2; nt++)
        bf[nt][kk] = *(const short8*)&Bs[(wc * 32 + nt * 16 + am) * 64 + kk * 32 + aq * 8];
    }
#pragma unroll
    for (int kk = 0; kk < 2; kk++)
#pragma unroll
      for (int mt = 0; mt < 4; mt++)
#pragma unroll
        for (int nt = 0; nt < 2; nt++)
          acc[mt][nt] = __builtin_amdgcn_mfma_f32_16x16x32_bf16(af[mt][kk], bf[nt][kk], acc[mt][nt], 0, 0, 0);
  }

#pragma unroll
  for (int mt = 0; mt < 4; mt++)
#pragma unroll
    for (int nt = 0; nt < 2; nt++)
#pragma unroll
      for (int reg = 0; reg < 4; reg++) {
        const int gm = m0 + wr * 64 + mt * 16 + aq * 4 + reg;
        const int gn = n0 + wc * 32 + nt * 16 + am;
        float val = acc[mt][nt][reg] + bias[gn];
        if (mode == 0) {
          outF[(size_t)gm * 1024 + gn] = val;
        } else {
          const int bb = gm >> 11, s = gm & 2047, h2 = gn >> 6, d = gn & 63;
          const size_t row = ((size_t)(bb * NH + h2)) * SEQ + s;
          if (mode == 2) {
            outBH[row * DKH + d] = val;
          } else {
            unsigned short h, l;
            split_hl(val, &h, &l);
            outHL[row * 128 + d] = h;
            outHL[row * 128 + 64 + d] = l;
          }
        }
      }
}

// ---------------------------------------------------------------------------
// Attention: split-bf16 MFMA QK^T + exact causal top-64 + sparse PV.
// Phase 2: one row/wave, keys register-resident. Selection uses a
// statistical probe (mu + z*sigma targeting count~128) to seed the exact
// bisection bracket -> ~2-3 count passes instead of ~10. PV double-buffered.
// ---------------------------------------------------------------------------
struct AttnSmem {
  float scores[8][SEQ];                 // 64 KB, raw scores (fallback path)
  float2 pl[8][LIST_CAP + 8];           // packed (p, j) kept list + zero pad
  float cand[8][64];
};

__global__ __launch_bounds__(512, 4)
void attn_topk(const unsigned short* __restrict__ qhl, const unsigned short* __restrict__ khl,
               const float* __restrict__ vp, unsigned short* __restrict__ aohl)
{
  __shared__ AttnSmem sm;
  const int t    = threadIdx.x;
  const int lane = t & 63;
  const int w    = t >> 6;            // 0..7
  const int bh   = blockIdx.x >> 8;
  const int rb   = 255 - (blockIdx.x & 255);   // heavy blocks dispatch first
  const int i0   = rb * 8;
  const unsigned short* qb = qhl + (size_t)bh * SEQ * 128;
  const unsigned short* kb = khl + (size_t)bh * SEQ * 128;
  const float* vbase = vp + (size_t)bh * SEQ * DKH;

  // ---- phase 1: MFMA QK^T into LDS scores (3-term split-bf16) ----
  const int am   = lane & 15;
  const int aq   = lane >> 4;
  const int dofs = aq * 8;

  short8 a_hi[2], a_lo[2];
#pragma unroll
  for (int c = 0; c < 2; c++) {
    size_t off = (size_t)(i0 + am) * 128 + c * 32 + dofs;  // rows 8..15 over-read -> next buffer, discarded
    a_hi[c] = *(const short8*)(qb + off);
    a_lo[c] = *(const short8*)(qb + off + 64);
  }

  const int T = (i0 >> 4) + 1;
  short8 b_hi[2], b_lo[2];
  int tt = w;
  if (tt < T) {
#pragma unroll
    for (int c = 0; c < 2; c++) {
      size_t off = (size_t)(tt * 16 + am) * 128 + c * 32 + dofs;
      b_hi[c] = *(const short8*)(kb + off);
      b_lo[c] = *(const short8*)(kb + off + 64);
    }
  }
  for (; tt < T; tt += 8) {
    short8 n_hi[2], n_lo[2];
    const int tn = tt + 8;
    if (tn < T) {
#pragma unroll
      for (int c = 0; c < 2; c++) {
        size_t off = (size_t)(tn * 16 + am) * 128 + c * 32 + dofs;
        n_hi[c] = *(const short8*)(kb + off);
        n_lo[c] = *(const short8*)(kb + off + 64);
      }
    } else {
#pragma unroll
      for (int c = 0; c < 2; c++) { n_hi[c] = b_hi[c]; n_lo[c] = b_lo[c]; }
    }
    f32x4 C = {0.0f, 0.0f, 0.0f, 0.0f};
#pragma unroll
    for (int c = 0; c < 2; c++) {
      C = __builtin_amdgcn_mfma_f32_16x16x32_bf16(a_hi[c], b_hi[c], C, 0, 0, 0);
      C = __builtin_amdgcn_mfma_f32_16x16x32_bf16(a_lo[c], b_hi[c], C, 0, 0, 0);
      C = __builtin_amdgcn_mfma_f32_16x16x32_bf16(a_hi[c], b_lo[c], C, 0, 0, 0);
    }
    if (aq < 2) {
      const int j = tt * 16 + am;
#pragma unroll
      for (int reg = 0; reg < 4; reg++) {
        const int rr = aq * 4 + reg;
        sm.scores[rr][j] = (j <= i0 + rr) ? C[reg] * 0.125f : NEGV;
      }
    }
#pragma unroll
    for (int c = 0; c < 2; c++) { b_hi[c] = n_hi[c]; b_lo[c] = n_lo[c]; }
  }
  __syncthreads();

  // ---- phase 2: one row per wave ----
  const int bb = bh >> 4, hh = bh & 15;
  const int r = w;
  const int i = i0 + w;

  // key load (stride-64, conflict-free) + row stats (mu, sigma, max)
  unsigned int keys[32];
#pragma unroll
  for (int u = 0; u < 32; u++) keys[u] = f2k(NEGV);
  float vmax = NEGV, s1 = 0.0f, s2 = 0.0f;
#pragma unroll
  for (int u = 0; u < 32; u++) {
    if ((u << 6) <= i) {               // wave-uniform causal guard
      const int j = (u << 6) + lane;
      float v = sm.scores[r][j];
      bool ok = (j <= i);
      float vm = ok ? v : NEGV;
      float va = ok ? v : 0.0f;
      vmax = fmaxf(vmax, vm);
      s1 += va;
      s2 = fmaf(va, va, s2);
      keys[u] = f2k(vm);
    }
  }
#pragma unroll
  for (int off = 32; off; off >>= 1) {
    vmax = fmaxf(vmax, __shfl_xor(vmax, off));
    s1 += __shfl_xor(s1, off);
    s2 += __shfl_xor(s2, off);
  }

  auto countge = [&](unsigned int km) -> int {
    int cnt = 0;
#pragma unroll
    for (int u = 0; u < 32; u++)
      if ((u << 6) <= i)
        cnt += __popcll(__ballot(keys[u] >= km));
    return cnt;
  };

  float vk;
  if (i + 1 <= 64) {
    vk = NEGV;                         // <=64 valid: keep all
  } else {
    const float n1  = (float)(i + 1);
    const float mu  = s1 / n1;
    const float sig = sqrtf(fmaxf(s2 / n1 - mu * mu, 0.0f));
    // inverse-normal probe targeting count ~128 (Hastings approx)
    const float qf = fminf(0.45f, 128.0f / n1);
    const float tq = sqrtf(-2.0f * __logf(qf));
    const float zq = tq - (2.30753f + 0.27061f * tq) /
                          (1.0f + tq * (0.99229f + 0.04481f * tq));
    unsigned int ka, kb2;
    int ca, cb;
    {
      const float t1 = mu + zq * sig;
      const unsigned int kt1 = f2k(t1);
      const int c1 = countge(kt1);
      if (c1 >= 64) { ka = kt1; ca = c1; kb2 = f2k(vmax) + 1u; cb = 0; }
      else {
        const float t2 = mu + (zq - 0.85f) * sig;
        const unsigned int kt2 = f2k(t2);
        const int c2 = countge(kt2);
        if (c2 >= 64) { ka = kt2; ca = c2; kb2 = kt1; cb = c1; }
        else { ka = f2k(-5000.0f); ca = i + 1; kb2 = kt2; cb = c2; }
      }
    }
    int guard = 0;
    while (kb2 - ka > 1u && (ca - cb) > 56 && guard < 64) {
      guard++;
      float fm = 0.5f * (k2f(ka) + k2f(kb2));
      unsigned int km = f2k(fm);
      if (km <= ka || km >= kb2) km = ka + ((kb2 - ka) >> 1);
      const int cnt = countge(km);
      if (cnt >= 64) { ka = km; ca = cnt; } else { kb2 = km; cb = cnt; }
    }
    if (kb2 - ka == 1u || (ca - cb) > 64) {
      vk = k2f(ka);                    // interval collapsed (dups) -> exact
    } else {
      int cbase = 0;
#pragma unroll
      for (int u = 0; u < 32; u++) {
        if ((u << 6) <= i) {
          unsigned int kx = keys[u];
          bool in = (kx >= ka && kx < kb2);
          unsigned long long mask = __ballot(in);
          if (in) sm.cand[w][cbase + lanecnt_lt(mask)] = k2f(kx);
          cbase += __popcll(mask);
        }
      }
      const int nc = cbase;            // <= 64 on this path
      float cv = (lane < nc) ? sm.cand[w][lane] : -3.4e38f;
      for (int ks = 2; ks <= 64; ks <<= 1) {
        for (int j2 = ks >> 1; j2 > 0; j2 >>= 1) {
          float other = __shfl_xor(cv, j2);
          bool up    = ((lane & ks) == 0);
          bool lower = ((lane & j2) == 0);
          float mn = fminf(cv, other), mx = fmaxf(cv, other);
          cv = (up == lower) ? mn : mx;
        }
      }
      int need = 64 - cb;
      vk = __shfl(cv, 64 - need);
    }
  }

  // softmax + packed (p, j) kept list
  float z = 0.0f;
  int base = 0;
#pragma unroll
  for (int u = 0; u < 32; u++) {
    if ((u << 6) <= i) {
      const int j = (u << 6) + lane;
      float sv = k2f(keys[u]);
      float p = (sv >= vk) ? __expf(sv - vmax) : 0.0f;  // NEG entries -> exactly 0
      z += p;
      unsigned long long mask = __ballot(p > 0.0f);
      if (p > 0.0f) {
        int pos = base + lanecnt_lt(mask);
        if (pos < LIST_CAP) {
          float2 e; e.x = p; e.y = __uint_as_float((unsigned int)j);
          sm.pl[r][pos] = e;
        }
      }
      base += __popcll(mask);
    }
  }
#pragma unroll
  for (int off = 32; off; off >>= 1) z += __shfl_xor(z, off);
  const float rz = 1.0f / z;

  // sparse PV: double-buffered batches of 8 (list prefetch + 8 gathers in flight)
  float acc = 0.0f;
  if (base <= LIST_CAP) {
    if (lane < 8) {                    // zero-pad so batches are branch-free
      float2 e; e.x = 0.0f; e.y = __uint_as_float(0u);
      sm.pl[r][base + lane] = e;
    }
    const int nb2 = (base + 7) >> 3;
    float2 cur[8], nxt[8];
#pragma unroll
    for (int s = 0; s < 8; s++) cur[s] = sm.pl[r][s];
    for (int b = 0; b < nb2; b++) {
      float vv[8];
#pragma unroll
      for (int s = 0; s < 8; s++) {
        const unsigned int jx = __float_as_uint(cur[s].y);
        vv[s] = vbase[(size_t)jx * DKH + lane];
      }
      const int nbase = (b + 1) * 8;
#pragma unroll
      for (int s = 0; s < 8; s++) {
        int idx = nbase + s; if (idx > LIST_CAP + 7) idx = 0;
        nxt[s] = sm.pl[r][idx];
      }
#pragma unroll
      for (int s = 0; s < 8; s++) acc = fmaf(cur[s].x, vv[s], acc);
#pragma unroll
      for (int s = 0; s < 8; s++) cur[s] = nxt[s];
    }
  } else {                             // ties pathology: dense (scores intact)
    for (int jx = 0; jx <= i; jx++) {
      float sv = sm.scores[r][jx];
      float p = (sv >= vk) ? __expf(sv - vmax) : 0.0f;
      acc = fmaf(p, vbase[(size_t)jx * DKH + lane], acc);
    }
  }

  // epilogue: write ao as hl planes (row-major M x 2048) for the final GEMM
  float val = acc * rz;
  unsigned short h, l;
  split_hl(val, &h, &l);
  const size_t arow = (size_t)(bb * SEQ + i) * 2048;
  aohl[arow + hh * 64 + lane] = h;
  aohl[arow + 1024 + hh * 64 + lane] = l;
}

// ---------------------------------------------------------------------------
extern "C" void kernel_launch(void* const* d_in, const int* in_sizes, int n_in,
                              void* d_out, int out_size, void* d_ws, size_t ws_size,
                              hipStream_t stream)
{
  const float* query = (const float*)d_in[0];
  const float* key   = (const float*)d_in[1];
  const float* value = (const float*)d_in[2];
  const float* Wq    = (const float*)d_in[3];
  const float* bq    = (const float*)d_in[4];
  const float* Wk    = (const float*)d_in[5];
  const float* bk    = (const float*)d_in[6];
  const float* Wv    = (const float*)d_in[7];
  const float* bv    = (const float*)d_in[8];
  const float* Wo    = (const float*)d_in[9];
  const float* bo    = (const float*)d_in[10];

  // ws (54.5 MB): xhl(16) | whl(4) | qhl(16) | khl(16). V fp32 lives in d_out
  // (scratch until the final GEMM overwrites it).
  unsigned short* xhl = (unsigned short*)d_ws;            // 4096 x 2048
  unsigned short* whl = xhl + (size_t)4096 * 2048;        // 1024 x 2048
  unsigned short* qhl = whl + (size_t)1024 * 2048;        // 65536 x 128 (bhsd hl)
  unsigned short* khl = qhl + (size_t)65536 * 128;
  float* vpf = (float*)d_out;                             // 65536 x 64 fp32 (bhsd)

  hipLaunchKernelGGL(conv_xhl, dim3(4096), dim3(256), 0, stream, query, xhl);
  hipLaunchKernelGGL(conv_whl, dim3(1024), dim3(256), 0, stream, Wq, whl);
  hipLaunchKernelGGL(gemm_mfma, dim3(512), dim3(256), 0, stream, xhl, whl, bq,
                     (float*)nullptr, qhl, (float*)nullptr, 1);
  hipLaunchKernelGGL(conv_xhl, dim3(4096), dim3(256), 0, stream, key, xhl);
  hipLaunchKernelGGL(conv_whl, dim3(1024), dim3(256), 0, stream, Wk, whl);
  hipLaunchKernelGGL(gemm_mfma, dim3(512), dim3(256), 0, stream, xhl, whl, bk,
                     (float*)nullptr, khl, (float*)nullptr, 1);
  hipLaunchKernelGGL(conv_xhl, dim3(4096), dim3(256), 0, stream, value, xhl);
  hipLaunchKernelGGL(conv_whl, dim3(1024), dim3(256), 0, stream, Wv, whl);
  hipLaunchKernelGGL(gemm_mfma, dim3(512), dim3(256), 0, stream, xhl, whl, bv,
                     (float*)nullptr, (unsigned short*)nullptr, vpf, 2);
  hipLaunchKernelGGL(attn_topk, dim3(8192), dim3(512), 0, stream, qhl, khl, vpf, xhl);
  hipLaunchKernelGGL(conv_whl, dim3(1024), dim3(256), 0, stream, Wo, whl);
  hipLaunchKernelGGL(gemm_mfma, dim3(512), dim3(256), 0, stream, xhl, whl, bo,
                     (float*)d_out, (unsigned short*)nullptr, (float*)nullptr, 0);
}